// Round 11
// baseline (571.270 us; speedup 1.0000x reference)
//
#include <hip/hip_runtime.h>

#define NDEV 8192
#define NAP  4
#define NSAMP 32768
#define EDD 262144
#define EDA 32768
#define EAD 32768
#define KC 128
#define ASTR2 132

typedef float vf2 __attribute__((ext_vector_type(2)));
static __device__ __forceinline__ vf2 pk_fma(vf2 a, vf2 b, vf2 c) {
    return __builtin_elementwise_fma(a, b, c);
}

using sh8 = __attribute__((ext_vector_type(8))) short;     // 8 bf16 (4 VGPRs)
using f32x4 = __attribute__((ext_vector_type(4))) float;   // 16x16 MFMA acc
using f32x16 = __attribute__((ext_vector_type(16))) float; // 32x32 MFMA acc

static __device__ __forceinline__ unsigned short bf16_rtne(float f) {
    unsigned u = __float_as_uint(f);
    u += 0x7fffu + ((u >> 16) & 1u);
    return (unsigned short)(u >> 16);
}
static __device__ __forceinline__ float bf16f(unsigned short h) {
    return __uint_as_float(((unsigned)h) << 16);
}

// ---------------------------------------------------------------------------
// Repack:
//  - conv2 weights -> 32x32 MFMA B-frags (bf16 hi/lo), uint4[(tap*2+s)*64+l]
//  - conv1 weights -> w1p (unchanged)
//  - fcW (2048x64) -> 16x16 MFMA B-frags with K-PERMUTATION k' = pos*32+oc
//      (inverse: k_orig = (k'&31)*64 + (k'>>5)); matches convfc's c2h layout.
//  - Wc (256x64) -> 16x16 MFMA B-frags, UNPERMUTED (emb layout standard).
// ---------------------------------------------------------------------------
__global__ void repack_kernel(const float* __restrict__ w2, float* __restrict__ wpk,
                              const float* __restrict__ w1, float* __restrict__ w1p,
                              const float* __restrict__ fcW, uint4* __restrict__ wfc,
                              const float* __restrict__ Wc, uint4* __restrict__ wcc)
{
    int i = blockIdx.x * 256 + threadIdx.x;
    if (i < 1152) {
        int lane = i & 63, s = (i >> 6) & 1, tap = i >> 7;
        int oc = lane & 31, g = lane >> 5;
        unsigned int d[4];
        #pragma unroll
        for (int d4 = 0; d4 < 4; ++d4) {
            unsigned short u01[2];
            #pragma unroll
            for (int h = 0; h < 2; ++h) {
                int e = 2 * d4 + h;
                int ic = g * 8 + e;
                float v = w2[oc * 144 + ic * 9 + tap];
                unsigned short hi = bf16_rtne(v);
                u01[h] = (s == 0) ? hi : bf16_rtne(v - bf16f(hi));
            }
            d[d4] = (unsigned)u01[0] | ((unsigned)u01[1] << 16);
        }
        ((uint4*)wpk)[i] = make_uint4(d[0], d[1], d[2], d[3]);
    }
    int j = i - 4608;
    if (j >= 0 && j < 288) {
        int h = j & 1, v = j >> 1;       // v = r*8 + o2
        int o2 = v & 7, r = v >> 3;      // r = ic*9+k in [0,18)
        w1p[j] = w1[(2 * o2 + h) * 18 + r];
    }
    // fc weight fragments (k-permuted for convfc's c2h layout)
    int h1 = i - 5120;
    if (h1 >= 0 && h1 < 32768) {
        int s = h1 & 1, l = (h1 >> 1) & 63, nt = (h1 >> 7) & 3, kstep = h1 >> 9;
        unsigned int d[4];
        #pragma unroll
        for (int d4 = 0; d4 < 4; ++d4) {
            unsigned short u01[2];
            #pragma unroll
            for (int hh = 0; hh < 2; ++hh) {
                int e = 2 * d4 + hh;
                int kp = kstep * 32 + (l >> 4) * 8 + e;      // permuted k'
                int korig = (kp & 31) * 64 + (kp >> 5);      // oc*64 + pos
                int n = nt * 16 + (l & 15);
                float v = fcW[(long)korig * 64 + n];
                unsigned short hi = bf16_rtne(v);
                u01[hh] = (s == 0) ? hi : bf16_rtne(v - bf16f(hi));
            }
            d[d4] = (unsigned)u01[0] | ((unsigned)u01[1] << 16);
        }
        wfc[h1] = make_uint4(d[0], d[1], d[2], d[3]);
    }
    int h2 = i - 37888;
    if (h2 >= 0 && h2 < 4096) {
        int s = h2 & 1, l = (h2 >> 1) & 63, nt = (h2 >> 7) & 3, kstep = h2 >> 9;
        unsigned int d[4];
        #pragma unroll
        for (int d4 = 0; d4 < 4; ++d4) {
            unsigned short u01[2];
            #pragma unroll
            for (int hh = 0; hh < 2; ++hh) {
                int e = 2 * d4 + hh;
                int k = kstep * 32 + (l >> 4) * 8 + e;
                int n = nt * 16 + (l & 15);
                float v = Wc[(long)k * 64 + n];
                unsigned short hi = bf16_rtne(v);
                u01[hh] = (s == 0) ? hi : bf16_rtne(v - bf16f(hi));
            }
            d[d4] = (unsigned)u01[0] | ((unsigned)u01[1] << 16);
        }
        wcc[h2] = make_uint4(d[0], d[1], d[2], d[3]);
    }
}

// ---------------------------------------------------------------------------
// Fused CSI encoder, PERSISTENT-BLOCK form: grid 256 (1 block/CU), each block
// loops over its 8 sample-groups.  Per-sample FP op sequence is BIT-IDENTICAL
// to the round-9 kernel.  vs round 10 (which failed): the per-iteration
// re-zero now covers the ENTIRE aliased region inpad+c1h = 135680 B = 8480
// uint4 (c1h is 16 samples x 4 planes x 960 shorts = 122880 B; round 10's
// 2720-uint4 zero left samples 4..15's conv halos corrupted by the previous
// iteration's c2h/red writes).  Loop-top barrier orders prev-iter epilogue
// reads before the re-zero.
// ---------------------------------------------------------------------------
#define C2STR 2052  /* c2h row stride in floats (2048 + 4 pad; %32==4) */
__global__ __launch_bounds__(1024) void convfc_kernel(
    const float* __restrict__ csi,
    const float* __restrict__ w1p, const float* __restrict__ b1,
    const float* __restrict__ wpk, const float* __restrict__ b2,
    const uint4* __restrict__ wfc, const float* __restrict__ fcb,
    float* __restrict__ emb)
{
    __shared__ __align__(16) char smem[135680];
    __shared__ float sw1p[288];
    __shared__ float sb1[16];
    __shared__ float sb2[32];
    __shared__ float sbF[64];
    float* inpad = (float*)smem;                              // [16][2][10][10]
    unsigned short* c1h = (unsigned short*)(smem + 12800);    // 16si x 4pl x 960 shorts
    float* c2h = (float*)smem;                                // [16][C2STR]
    float* red = (float*)smem;                                // [128][64] epilogue
    const int tid = threadIdx.x;
    const int lane = tid & 63;
    const int w = __builtin_amdgcn_readfirstlane(tid >> 6);   // wave 0..15

    // one-time staging (block-invariant)
    for (int i = tid; i < 288; i += 1024) sw1p[i] = w1p[i];
    if (tid < 16) sb1[tid] = b1[tid];
    if (tid < 32) sb2[tid] = b2[tid];
    if (tid < 64) sbF[tid] = fcb[tid];

    const int rr = lane & 31, g = lane >> 5;
    const int p0f = rr >> 3, pt = rr & 7;
    const int p1f = 4 + p0f;
    const int ks = w & 7;
    const int ntb = (w >> 3) * 2;    // 0 or 2
    const int mrow = lane & 15;
    const int g2 = lane >> 4;

    #pragma unroll 1
    for (int it = 0; it < 8; ++it) {
        const long s0 = ((long)blockIdx.x * 8 + it) * 16;

        __syncthreads();   // prev-iter epilogue reads done before re-zero
        {   // zero inpad + c1h FULLY (12800B + 122880B = 135680B = 8480 uint4)
            const uint4 z4 = make_uint4(0u, 0u, 0u, 0u);
            uint4* zz = (uint4*)smem;
            for (int i = tid; i < 8480; i += 1024) zz[i] = z4;
        }
        __syncthreads();

        for (int i = tid; i < 2048; i += 1024) {
            int si = i >> 7, r = i & 127;
            int f = r >> 4, t = (r >> 1) & 7, c = r & 1;
            inpad[si * 200 + c * 100 + (f + 1) * 10 + (t + 1)] = csi[s0 * 128 + i];
        }
        __syncthreads();

        // ---- conv1: wave w = sample w, thread = (f1, t1), all 16 ocs ----
        {
            const int si1 = w;
            const int p1 = lane;
            const int f1 = p1 >> 3, t1 = p1 & 7;
            float inv[18];
            #pragma unroll
            for (int ic = 0; ic < 2; ++ic)
                #pragma unroll
                for (int df = 0; df < 3; ++df)
                    #pragma unroll
                    for (int dt = 0; dt < 3; ++dt)
                        inv[ic * 9 + df * 3 + dt] =
                            inpad[si1 * 200 + ic * 100 + (f1 + df) * 10 + (t1 + dt)];
            vf2 a1[8];
            #pragma unroll
            for (int o2 = 0; o2 < 8; ++o2) a1[o2] = (vf2){sb1[2 * o2], sb1[2 * o2 + 1]};
            const vf2* sw1v = (const vf2*)sw1p;
            #pragma unroll
            for (int r = 0; r < 18; ++r) {
                vf2 xv = {inv[r], inv[r]};
                #pragma unroll
                for (int o2 = 0; o2 < 8; ++o2)
                    a1[o2] = pk_fma(xv, sw1v[r * 8 + o2], a1[o2]);
            }
            float v[16];
            #pragma unroll
            for (int o2 = 0; o2 < 8; ++o2) {
                v[2 * o2]     = fmaxf(a1[o2].x, 0.f);
                v[2 * o2 + 1] = fmaxf(a1[o2].y, 0.f);
            }
            const int cell = ((f1 + 1) * 12 + (t1 + 1)) * 8;
            #pragma unroll
            for (int gg = 0; gg < 2; ++gg) {
                unsigned int hd[4], ld[4];
                #pragma unroll
                for (int d = 0; d < 4; ++d) {
                    float x0 = v[gg * 8 + 2 * d], x1 = v[gg * 8 + 2 * d + 1];
                    unsigned short h0 = bf16_rtne(x0), h1 = bf16_rtne(x1);
                    unsigned short l0 = bf16_rtne(x0 - bf16f(h0));
                    unsigned short l1 = bf16_rtne(x1 - bf16f(h1));
                    hd[d] = (unsigned)h0 | ((unsigned)h1 << 16);
                    ld[d] = (unsigned)l0 | ((unsigned)l1 << 16);
                }
                *(uint4*)&c1h[(si1 * 4 + gg) * 960 + cell]     = make_uint4(hd[0], hd[1], hd[2], hd[3]);
                *(uint4*)&c1h[(si1 * 4 + 2 + gg) * 960 + cell] = make_uint4(ld[0], ld[1], ld[2], ld[3]);
            }
        }

        // preload conv2 B fragments (L2-hot) while waiting on the barrier
        sh8 Bh[9], Bl[9];
        {
            const sh8* bfp = (const sh8*)wpk;
            #pragma unroll
            for (int tap = 0; tap < 9; ++tap) {
                Bh[tap] = bfp[(tap * 2 + 0) * 64 + lane];
                Bl[tap] = bfp[(tap * 2 + 1) * 64 + lane];
            }
        }
        __syncthreads();

        // ---- conv2: wave w = sample w ----
        {
            const int s = w;
            const float bias2 = sb2[rr];
            f32x16 acc0, acc1;
            #pragma unroll
            for (int u = 0; u < 16; ++u) { acc0[u] = bias2; acc1[u] = bias2; }
            const int hb = (s * 4 + g) * 960;
            const int lb = (s * 4 + 2 + g) * 960;
            #pragma unroll
            for (int df = 0; df < 3; ++df) {
                #pragma unroll
                for (int dt = 0; dt < 3; ++dt) {
                    const int tap = df * 3 + dt;
                    const int c0 = ((p0f + df) * 12 + (pt + dt)) * 8;
                    const int c1i = ((p1f + df) * 12 + (pt + dt)) * 8;
                    sh8 Ah0 = *(const sh8*)&c1h[hb + c0];
                    sh8 Al0 = *(const sh8*)&c1h[lb + c0];
                    sh8 Ah1 = *(const sh8*)&c1h[hb + c1i];
                    sh8 Al1 = *(const sh8*)&c1h[lb + c1i];
                    acc0 = __builtin_amdgcn_mfma_f32_32x32x16_bf16(Ah0, Bh[tap], acc0, 0, 0, 0);
                    acc1 = __builtin_amdgcn_mfma_f32_32x32x16_bf16(Ah1, Bh[tap], acc1, 0, 0, 0);
                    acc0 = __builtin_amdgcn_mfma_f32_32x32x16_bf16(Ah0, Bl[tap], acc0, 0, 0, 0);
                    acc1 = __builtin_amdgcn_mfma_f32_32x32x16_bf16(Ah1, Bl[tap], acc1, 0, 0, 0);
                    acc0 = __builtin_amdgcn_mfma_f32_32x32x16_bf16(Al0, Bh[tap], acc0, 0, 0, 0);
                    acc1 = __builtin_amdgcn_mfma_f32_32x32x16_bf16(Al1, Bh[tap], acc1, 0, 0, 0);
                }
            }
            __syncthreads();   // ALL c1h reads complete before ANY c2h write
            float* crow = c2h + (size_t)s * C2STR;
            #pragma unroll
            for (int i = 0; i < 16; ++i) {
                const int pos = (i & 3) + 8 * (i >> 2) + 4 * g;
                crow[pos * 32 + rr]        = fmaxf(acc0[i], 0.f);
                crow[(pos + 32) * 32 + rr] = fmaxf(acc1[i], 0.f);
            }
        }
        __syncthreads();

        // ---- fc stage: wave w -> ks = w&7, nt in {ntb, ntb+1} ----
        f32x4 acc[2];
        #pragma unroll
        for (int ni = 0; ni < 2; ++ni) acc[ni] = (f32x4){0.f, 0.f, 0.f, 0.f};
        #pragma unroll
        for (int t = 0; t < 8; ++t) {
            const int kstep = ks * 8 + t;
            const uint4* bp = wfc + (size_t)kstep * 512 + lane * 2;
            uint4 bh0 = bp[ntb * 128],       bl0 = bp[ntb * 128 + 1];
            uint4 bh1 = bp[(ntb + 1) * 128], bl1 = bp[(ntb + 1) * 128 + 1];
            const float4 a0 = *(const float4*)&c2h[mrow * C2STR + kstep * 32 + g2 * 8];
            const float4 a1 = *(const float4*)&c2h[mrow * C2STR + kstep * 32 + g2 * 8 + 4];
            float av[8] = {a0.x, a0.y, a0.z, a0.w, a1.x, a1.y, a1.z, a1.w};
            unsigned short hs[8], lss[8];
            #pragma unroll
            for (int e = 0; e < 8; ++e) {
                hs[e] = bf16_rtne(av[e]);
                lss[e] = bf16_rtne(av[e] - bf16f(hs[e]));
            }
            sh8 Ah = {(short)hs[0], (short)hs[1], (short)hs[2], (short)hs[3],
                      (short)hs[4], (short)hs[5], (short)hs[6], (short)hs[7]};
            sh8 Al = {(short)lss[0], (short)lss[1], (short)lss[2], (short)lss[3],
                      (short)lss[4], (short)lss[5], (short)lss[6], (short)lss[7]};
            acc[0] = __builtin_amdgcn_mfma_f32_16x16x32_bf16(Ah, *(const sh8*)&bh0, acc[0], 0, 0, 0);
            acc[0] = __builtin_amdgcn_mfma_f32_16x16x32_bf16(Ah, *(const sh8*)&bl0, acc[0], 0, 0, 0);
            acc[0] = __builtin_amdgcn_mfma_f32_16x16x32_bf16(Al, *(const sh8*)&bh0, acc[0], 0, 0, 0);
            acc[1] = __builtin_amdgcn_mfma_f32_16x16x32_bf16(Ah, *(const sh8*)&bh1, acc[1], 0, 0, 0);
            acc[1] = __builtin_amdgcn_mfma_f32_16x16x32_bf16(Ah, *(const sh8*)&bl1, acc[1], 0, 0, 0);
            acc[1] = __builtin_amdgcn_mfma_f32_16x16x32_bf16(Al, *(const sh8*)&bh1, acc[1], 0, 0, 0);
        }
        __syncthreads();   // c2h dead; red aliases it
        #pragma unroll
        for (int ni = 0; ni < 2; ++ni) {
            const int nt = ntb + ni;
            #pragma unroll
            for (int r = 0; r < 4; ++r)
                red[(ks * 16 + g2 * 4 + r) * 64 + nt * 16 + mrow] = acc[ni][r];
        }
        __syncthreads();
        if (tid < 256) {
            const int m = tid >> 4, oq = tid & 15;
            float4 sum;
            sum.x = sbF[oq * 4 + 0]; sum.y = sbF[oq * 4 + 1];
            sum.z = sbF[oq * 4 + 2]; sum.w = sbF[oq * 4 + 3];
            #pragma unroll
            for (int jq = 0; jq < 8; ++jq) {
                float4 rv = *(float4*)&red[(jq * 16 + m) * 64 + oq * 4];
                sum.x += rv.x; sum.y += rv.y; sum.z += rv.z; sum.w += rv.w;
            }
            float4 o4;
            o4.x = fmaxf(sum.x, 0.f); o4.y = fmaxf(sum.y, 0.f);
            o4.z = fmaxf(sum.z, 0.f); o4.w = fmaxf(sum.w, 0.f);
            *(float4*)&emb[(s0 + m) * 64 + oq * 4] = o4;
        }
    }
}

// ---------------------------------------------------------------------------
// fc16 via 16x16x32 bf16 MFMA (round-5 proven form) — used for Wc stage.
// ---------------------------------------------------------------------------
__global__ __launch_bounds__(256) void fc16_kernel(
    const float* __restrict__ A, const uint4* __restrict__ Wfrag,
    const float* __restrict__ bias, float* __restrict__ out, int K)
{
    __shared__ __align__(16) float smem[4224];
    float* As = smem;
    const int tid = threadIdx.x;
    const long m0g = (long)blockIdx.x * 16;
    const int ks = tid >> 6;
    const int lane = tid & 63;
    const int mrow = lane & 15;
    const int g = lane >> 4;

    f32x4 acc[4];
    #pragma unroll
    for (int nt = 0; nt < 4; ++nt) acc[nt] = (f32x4){0.f, 0.f, 0.f, 0.f};

    for (int kc = 0; kc < K; kc += KC) {
        __syncthreads();
        #pragma unroll
        for (int i = 0; i < 2; ++i) {
            int idx = tid + i * 256;
            int m = idx >> 5, kq = idx & 31;
            float4 v = *(const float4*)&A[(m0g + m) * K + kc + kq * 4];
            *(float4*)&As[m * ASTR2 + kq * 4] = v;
        }
        __syncthreads();
        const int kstep = (kc >> 5) + ks;
        const uint4* bp = Wfrag + (size_t)kstep * 512 + lane * 2;
        uint4 bh0 = bp[0],   bl0 = bp[1];
        uint4 bh1 = bp[128], bl1 = bp[129];
        uint4 bh2 = bp[256], bl2 = bp[257];
        uint4 bh3 = bp[384], bl3 = bp[385];
        const float4 a0 = *(const float4*)&As[mrow * ASTR2 + ks * 32 + g * 8];
        const float4 a1 = *(const float4*)&As[mrow * ASTR2 + ks * 32 + g * 8 + 4];
        float av[8] = {a0.x, a0.y, a0.z, a0.w, a1.x, a1.y, a1.z, a1.w};
        unsigned short hs[8], lss[8];
        #pragma unroll
        for (int e = 0; e < 8; ++e) {
            hs[e] = bf16_rtne(av[e]);
            lss[e] = bf16_rtne(av[e] - bf16f(hs[e]));
        }
        sh8 Ah = {(short)hs[0], (short)hs[1], (short)hs[2], (short)hs[3],
                  (short)hs[4], (short)hs[5], (short)hs[6], (short)hs[7]};
        sh8 Al = {(short)lss[0], (short)lss[1], (short)lss[2], (short)lss[3],
                  (short)lss[4], (short)lss[5], (short)lss[6], (short)lss[7]};
        #define FCMM(ntv, bhv, blv) \
            acc[ntv] = __builtin_amdgcn_mfma_f32_16x16x32_bf16(Ah, *(const sh8*)&(bhv), acc[ntv], 0, 0, 0); \
            acc[ntv] = __builtin_amdgcn_mfma_f32_16x16x32_bf16(Ah, *(const sh8*)&(blv), acc[ntv], 0, 0, 0); \
            acc[ntv] = __builtin_amdgcn_mfma_f32_16x16x32_bf16(Al, *(const sh8*)&(bhv), acc[ntv], 0, 0, 0);
        FCMM(0, bh0, bl0)
        FCMM(1, bh1, bl1)
        FCMM(2, bh2, bl2)
        FCMM(3, bh3, bl3)
        #undef FCMM
    }
    __syncthreads();
    float* red = smem;
    #pragma unroll
    for (int nt = 0; nt < 4; ++nt)
        #pragma unroll
        for (int r = 0; r < 4; ++r)
            red[(ks * 16 + g * 4 + r) * 64 + nt * 16 + mrow] = acc[nt][r];
    __syncthreads();
    {
        int m = tid >> 4, oq = tid & 15;
        float4 r0 = *(float4*)&red[(0 * 16 + m) * 64 + oq * 4];
        float4 r1 = *(float4*)&red[(1 * 16 + m) * 64 + oq * 4];
        float4 r2 = *(float4*)&red[(2 * 16 + m) * 64 + oq * 4];
        float4 r3 = *(float4*)&red[(3 * 16 + m) * 64 + oq * 4];
        const float4 b4 = *(const float4*)&bias[oq * 4];
        float4 o4;
        o4.x = fmaxf(r0.x + r1.x + r2.x + r3.x + b4.x, 0.f);
        o4.y = fmaxf(r0.y + r1.y + r2.y + r3.y + b4.y, 0.f);
        o4.z = fmaxf(r0.z + r1.z + r2.z + r3.z + b4.z, 0.f);
        o4.w = fmaxf(r0.w + r1.w + r2.w + r3.w + b4.w, 0.f);
        *(float4*)&out[(m0g + m) * 64 + oq * 4] = o4;
    }
}

// ---------------------------------------------------------------------------
// Device merge + fused xnorm; block 0 additionally computes the AP encoder.
// ---------------------------------------------------------------------------
__global__ __launch_bounds__(256) void merge_kernel(
    const float* __restrict__ dpos, const int* __restrict__ pkts,
    const float* __restrict__ csif,
    const float* __restrict__ Wp, const float* __restrict__ bp,
    const float* __restrict__ Wm, const float* __restrict__ bm,
    const int* __restrict__ degout,
    float* __restrict__ hdev, float* __restrict__ xn,
    const float* __restrict__ appos, const float* __restrict__ Wap,
    const float* __restrict__ bap, const int* __restrict__ degapo,
    float* __restrict__ hap, float* __restrict__ xnap)
{
    __shared__ float sWm[80][64];
    __shared__ float spos[4][16];
    __shared__ float scf[4][64];
    const int tid = threadIdx.x;
    for (int i = tid; i < 5120; i += 256) sWm[i >> 6][i & 63] = Wm[i];
    const int n0 = blockIdx.x * 4;
    (&scf[0][0])[tid] = csif[(long)n0 * 64 + tid];
    if (tid < 64) {
        int dl = tid >> 4, o = tid & 15;
        int d = n0 + dl;
        float px = dpos[d * 2], py = dpos[d * 2 + 1], pk = (float)pkts[d];
        float v = bp[o] + px * Wp[o] + py * Wp[16 + o] + pk * Wp[32 + o];
        spos[dl][o] = fmaxf(v, 0.f);
    }
    __syncthreads();
    const int o = tid & 63, dl = tid >> 6;
    float h = bm[o];
    #pragma unroll
    for (int j = 0; j < 16; ++j) h += spos[dl][j] * sWm[j][o];
    #pragma unroll 8
    for (int j = 0; j < 64; ++j) h += scf[dl][j] * sWm[16 + j][o];
    h = fmaxf(h, 0.f);
    const long idx = (long)(n0 + dl) * 64 + o;
    hdev[idx] = h;
    xn[idx] = h * rsqrtf(fmaxf((float)degout[n0 + dl], 1.f));
    if (blockIdx.x == 0) {
        int a = tid >> 6, oo = tid & 63;
        float v = fmaxf(bap[oo] + appos[a * 2] * Wap[oo] + appos[a * 2 + 1] * Wap[64 + oo], 0.f);
        hap[tid] = v;
        xnap[tid] = v * rsqrtf(fmaxf((float)degapo[a], 1.f));
    }
}

// ---------------------------------------------------------------------------
__global__ __launch_bounds__(256) void degrees_kernel(
    const int* __restrict__ dd_src, const int* __restrict__ dd_dst,
    const int* __restrict__ da_src, const int* __restrict__ da_dst,
    const int* __restrict__ ad_src, const int* __restrict__ ad_dst,
    int* deg_dd_out, int* deg_dd_in, int* deg_da_out, int* deg_ad_in, int* deg_small)
{
    __shared__ int s4[16];
    const int tid = threadIdx.x;
    if (tid < 16) s4[tid] = 0;
    __syncthreads();
    const int gid = blockIdx.x * 256 + tid;
    atomicAdd(&deg_dd_out[dd_src[gid]], 1);
    atomicAdd(&deg_dd_in[dd_dst[gid]], 1);
    if (gid < EDA) {
        atomicAdd(&deg_da_out[da_src[gid]], 1);
        atomicAdd(&s4[da_dst[gid]], 1);
        atomicAdd(&s4[8 + ad_src[gid]], 1);
        atomicAdd(&deg_ad_in[ad_dst[gid]], 1);
    }
    __syncthreads();
    if (tid < 16 && s4[tid] != 0) atomicAdd(&deg_small[tid], s4[tid]);
}

__global__ __launch_bounds__(1024) void scan_kernel(
    const int* __restrict__ degA, int* rsA, int* curA,
    const int* __restrict__ degB, int* rsB, int* curB)
{
    const int* deg = blockIdx.x ? degB : degA;
    int* rs = blockIdx.x ? rsB : rsA;
    int* cur = blockIdx.x ? curB : curA;
    __shared__ int sd[1024];
    const int tid = threadIdx.x;
    const int base = tid * 8;
    int v[8]; int s = 0;
    #pragma unroll
    for (int j = 0; j < 8; ++j) { v[j] = deg[base + j]; s += v[j]; }
    sd[tid] = s;
    __syncthreads();
    for (int off = 1; off < 1024; off <<= 1) {
        int t = (tid >= off) ? sd[tid - off] : 0;
        __syncthreads();
        sd[tid] += t;
        __syncthreads();
    }
    int ex = sd[tid] - s;
    #pragma unroll
    for (int j = 0; j < 8; ++j) { rs[base + j] = ex; cur[base + j] = ex; ex += v[j]; }
}

__global__ __launch_bounds__(256) void reorder_kernel(
    const int* __restrict__ src, const int* __restrict__ dst,
    int* __restrict__ cursor, int* __restrict__ ssrc, int nE)
{
    int e = blockIdx.x * 256 + threadIdx.x;
    if (e < nE) {
        int pos = atomicAdd(&cursor[dst[e]], 1);
        ssrc[pos] = src[e];
    }
}

// ---------------------------------------------------------------------------
// Fused gather launch: blocks [0,512) dd (16 devices/block), [512,1024) ad,
// [1024,1280) da LDS-reduce (layer 1 only).  (round-6 proven form)
// ---------------------------------------------------------------------------
__global__ __launch_bounds__(256) void gatherx_kernel(
    const int* __restrict__ rsdd, const int* __restrict__ degddi,
    const int* __restrict__ ssdd, const float* __restrict__ xn, float* __restrict__ aggdd,
    const int* __restrict__ rsad, const int* __restrict__ degadi,
    const int* __restrict__ ssad, const float* __restrict__ xnap, float* __restrict__ aggad,
    const int* __restrict__ da_src, const int* __restrict__ da_dst,
    const float* __restrict__ hdev, const int* __restrict__ degdao,
    float* __restrict__ aggda)
{
    __shared__ float sacc[4][64];
    const int b = blockIdx.x;
    const int tid = threadIdx.x;
    if (b < 1024) {
        const bool isdd = b < 512;
        const int lane = tid & 63;
        const int gbase = lane & 48;
        const int lg = lane & 15;
        const int fq = lg * 4;
        const int d = (isdd ? b : b - 512) * 16 + (tid >> 4);
        const int* rs = isdd ? rsdd : rsad;
        const int* dg = isdd ? degddi : degadi;
        const int* ss = isdd ? ssdd : ssad;
        const float* x = isdd ? xn : xnap;
        float* agg = isdd ? aggdd : aggad;
        const int start = rs[d], len = dg[d];
        float ax = 0.f, ay = 0.f, az = 0.f, aw = 0.f;
        for (int j = 0; j < len; j += 16) {
            const int rem = min(16, len - j);
            const int myidx = ss[start + j + min(lg, rem - 1)];
            float4 v[16];
            #pragma unroll
            for (int k = 0; k < 16; ++k) {
                const int sk = __shfl(myidx, gbase + min(k, rem - 1), 64);
                v[k] = *(const float4*)&x[(long)sk * 64 + fq];
            }
            #pragma unroll
            for (int k = 0; k < 16; ++k) {
                const float m = (k < rem) ? 1.f : 0.f;
                ax += m * v[k].x; ay += m * v[k].y;
                az += m * v[k].z; aw += m * v[k].w;
            }
        }
        const float sc = rsqrtf(fmaxf((float)len, 1.f));
        float4 o;
        o.x = ax * sc; o.y = ay * sc; o.z = az * sc; o.w = aw * sc;
        *(float4*)&agg[(long)d * 64 + fq] = o;
    } else {
        (&sacc[0][0])[tid] = 0.f;
        __syncthreads();
        const int f = tid & 63;
        const int base = (b - 1024) * 128;
        for (int e = base + (tid >> 6); e < base + 128; e += 4) {
            int s = da_src[e], d = da_dst[e];
            float sc = rsqrtf(fmaxf((float)degdao[s], 1.f));
            atomicAdd(&sacc[d][f], hdev[(long)s * 64 + f] * sc);
        }
        __syncthreads();
        float v = (&sacc[0][0])[tid];
        if (v != 0.f) atomicAdd(&aggda[tid], v);
    }
}

// ---------------------------------------------------------------------------
// Fused combine: blocks [0,2048) hd (two relations); block 2048 (layer 1) ha.
// ---------------------------------------------------------------------------
__global__ __launch_bounds__(256) void combinex_kernel(
    const float* __restrict__ agg1, const float* __restrict__ W1, const float* __restrict__ b1,
    const float* __restrict__ agg2, const float* __restrict__ W2, const float* __restrict__ b2,
    const int* __restrict__ degout, float* __restrict__ out, float* __restrict__ xnout,
    const float* __restrict__ aggda, const int* __restrict__ degdai,
    const float* __restrict__ Wda, const float* __restrict__ bda,
    const int* __restrict__ degapo, float* __restrict__ ha_out, float* __restrict__ ha_xn)
{
    __shared__ float sW1[64][64];
    __shared__ float sW2[64][64];
    __shared__ float sa1[4][64];
    __shared__ float sa2[4][64];
    const int tid = threadIdx.x;
    if (blockIdx.x < 2048) {
        for (int i = tid; i < 4096; i += 256) { sW1[i >> 6][i & 63] = W1[i]; sW2[i >> 6][i & 63] = W2[i]; }
        const int n0 = blockIdx.x * 4;
        (&sa1[0][0])[tid] = agg1[(long)n0 * 64 + tid];
        (&sa2[0][0])[tid] = agg2[(long)n0 * 64 + tid];
        __syncthreads();
        const int o = tid & 63, dl = tid >> 6;
        float acc1 = 0.f, acc2 = 0.f;
        #pragma unroll 8
        for (int k = 0; k < 64; ++k) {
            acc1 += sa1[dl][k] * sW1[k][o];
            acc2 += sa2[dl][k] * sW2[k][o];
        }
        float h = fmaxf(acc1 + acc2 + b1[o] + b2[o], 0.f);
        const long idx = (long)(n0 + dl) * 64 + o;
        out[idx] = h;
        if (xnout) xnout[idx] = h * rsqrtf(fmaxf((float)degout[n0 + dl], 1.f));
    } else {
        const int o = tid & 63, a = tid >> 6;
        float acc = 0.f;
        for (int k = 0; k < 64; ++k) acc += aggda[a * 64 + k] * Wda[k * 64 + o];
        float r = rsqrtf(fmaxf((float)degdai[a], 1.f));
        float h = fmaxf(acc * r + bda[o], 0.f);
        ha_out[tid] = h;
        ha_xn[tid] = h * rsqrtf(fmaxf((float)degapo[a], 1.f));
    }
}

// ---------------------------------------------------------------------------
__global__ __launch_bounds__(256) void head_kernel(
    const float* __restrict__ hd2,
    const float* __restrict__ W1, const float* __restrict__ b1,
    const float* __restrict__ W2, const float* __restrict__ b2,
    float* __restrict__ logits_out)
{
    __shared__ float sW1[64][64];
    __shared__ float sW2[64][32];
    __shared__ float sh[4][64];
    __shared__ float st[4][64];
    const int tid = threadIdx.x;
    for (int i = tid; i < 4096; i += 256) sW1[i >> 6][i & 63] = W1[i];
    for (int i = tid; i < 2048; i += 256) sW2[i >> 5][i & 31] = W2[i];
    const int n0 = blockIdx.x * 4;
    (&sh[0][0])[tid] = hd2[(long)n0 * 64 + tid];
    __syncthreads();
    const int o = tid & 63, dl = tid >> 6;
    float acc = b1[o];
    #pragma unroll 8
    for (int k = 0; k < 64; ++k) acc += sh[dl][k] * sW1[k][o];
    st[dl][o] = fmaxf(acc, 0.f);
    __syncthreads();
    if (tid < 128) {
        int j = tid & 31, d2 = tid >> 5;
        float a2 = b2[j];
        #pragma unroll 8
        for (int k = 0; k < 64; ++k) a2 += st[d2][k] * sW2[k][j];
        logits_out[(long)(n0 + d2) * 32 + j] = a2;
    }
}

// ---------------------------------------------------------------------------
__global__ __launch_bounds__(1024) void softmax_stats_kernel(
    const float* __restrict__ logits,
    float* __restrict__ smax, int* __restrict__ sargm, float* __restrict__ ssum)
{
    __shared__ float smx[1024];
    __shared__ int sid[1024];
    __shared__ float ssm[1024];
    const int j = blockIdx.x;
    const int tid = threadIdx.x;
    float best = -__builtin_inff(); int bid = 0x7fffffff;
    for (int n = tid; n < NDEV; n += 1024) {
        float v = logits[n * 32 + j];
        if (v > best) { best = v; bid = n; }
    }
    smx[tid] = best; sid[tid] = bid;
    __syncthreads();
    for (int s = 512; s > 0; s >>= 1) {
        if (tid < s) {
            float v2 = smx[tid + s]; int i2 = sid[tid + s];
            if (v2 > smx[tid] || (v2 == smx[tid] && i2 < sid[tid])) { smx[tid] = v2; sid[tid] = i2; }
        }
        __syncthreads();
    }
    const float mx = smx[0];
    float part = 0.f;
    for (int n = tid; n < NDEV; n += 1024) part += expf(logits[n * 32 + j] - mx);
    ssm[tid] = part;
    __syncthreads();
    for (int s = 512; s > 0; s >>= 1) {
        if (tid < s) ssm[tid] += ssm[tid + s];
        __syncthreads();
    }
    if (tid == 0) { smax[j] = mx; sargm[j] = sid[0]; ssum[j] = ssm[0]; }
}

__global__ __launch_bounds__(256) void final_kernel(
    const float* __restrict__ logits, const float* __restrict__ smax,
    const int* __restrict__ sargm, const float* __restrict__ ssum,
    float* __restrict__ hard, float* __restrict__ soft)
{
    const int gid = blockIdx.x * 256 + threadIdx.x;
    const int n = gid >> 3, t = gid & 7;
    float s = 0.f; int h = 0;
    #pragma unroll
    for (int a = 0; a < 4; ++a) {
        int j = t * 4 + a;
        s += expf(logits[n * 32 + j] - smax[j]) / ssum[j];
        h |= (sargm[j] == n) ? 1 : 0;
    }
    hard[gid] = (float)h;
    soft[gid] = s;
}

// ---------------------------------------------------------------------------
extern "C" void kernel_launch(void* const* d_in, const int* in_sizes, int n_in,
                              void* d_out, int out_size, void* d_ws, size_t ws_size,
                              hipStream_t stream)
{
    const float* device_pos = (const float*)d_in[0];
    const float* ap_pos     = (const float*)d_in[1];
    const float* csi        = (const float*)d_in[2];
    const int*   node_pk    = (const int*)d_in[3];
    const int* dd_src = (const int*)d_in[4];
    const int* dd_dst = (const int*)d_in[5];
    const int* da_src = (const int*)d_in[6];
    const int* da_dst = (const int*)d_in[7];
    const int* ad_src = (const int*)d_in[8];
    const int* ad_dst = (const int*)d_in[9];
    const float* w1  = (const float*)d_in[10]; const float* b1  = (const float*)d_in[11];
    const float* w2  = (const float*)d_in[12]; const float* b2  = (const float*)d_in[13];
    const float* fcW = (const float*)d_in[14]; const float* fcb = (const float*)d_in[15];
    const float* Wp  = (const float*)d_in[16]; const float* bp  = (const float*)d_in[17];
    const float* Wc  = (const float*)d_in[18]; const float* bc  = (const float*)d_in[19];
    const float* Wm  = (const float*)d_in[20]; const float* bm  = (const float*)d_in[21];
    const float* Wap = (const float*)d_in[22]; const float* bap = (const float*)d_in[23];
    const float* g1ddW = (const float*)d_in[24]; const float* g1ddb = (const float*)d_in[25];
    const float* g1daW = (const float*)d_in[26]; const float* g1dab = (const float*)d_in[27];
    const float* g1adW = (const float*)d_in[28]; const float* g1adb = (const float*)d_in[29];
    const float* g2ddW = (const float*)d_in[30]; const float* g2ddb = (const float*)d_in[31];
    const float* g2adW = (const float*)d_in[34]; const float* g2adb = (const float*)d_in[35];
    const float* a1W = (const float*)d_in[36]; const float* a1b = (const float*)d_in[37];
    const float* a2W = (const float*)d_in[38]; const float* a2b = (const float*)d_in[39];

    float* ws = (float*)d_ws;
    size_t o_emb   = 0;                               // 2,097,152
    size_t o_csif  = o_emb + (size_t)NSAMP * 64;
    size_t o_hdev  = o_csif + (size_t)NDEV * 64;
    size_t o_hap   = o_hdev + (size_t)NDEV * 64;      // 256
    size_t o_hd1   = o_hap + 256;
    size_t o_ha1   = o_hd1 + (size_t)NDEV * 64;       // 256
    size_t o_hd2   = o_ha1 + 256;
    size_t o_aggdd = o_hd2 + (size_t)NDEV * 64;
    size_t o_aggad = o_aggdd + (size_t)NDEV * 64;
    size_t o_xn    = o_aggad + (size_t)NDEV * 64;
    size_t o_xnap  = o_xn + (size_t)NDEV * 64;        // 256
    size_t o_wpk   = o_xnap + 256;                    // 4608 (conv MFMA B-frags)
    size_t o_w1p   = o_wpk + 4608;                    // 288
    size_t o_wfc   = o_w1p + 288;                     // 131072 (fcW MFMA frags, permuted)
    size_t o_wcc   = o_wfc + 131072;                  // 16384 (Wc MFMA frags)
    // zero region
    size_t o_zero  = o_wcc + 16384;
    size_t o_degddo = o_zero;
    size_t o_degddi = o_degddo + NDEV;
    size_t o_degdao = o_degddi + NDEV;
    size_t o_degadi = o_degdao + NDEV;
    size_t o_degsm  = o_degadi + NDEV;        // int[16]
    size_t o_aggda  = o_degsm + 16;           // float[256]
    size_t o_zend   = o_aggda + 256;
    // non-zeroed
    size_t o_rsdd  = o_zend;
    size_t o_curdd = o_rsdd + NDEV;
    size_t o_rsad  = o_curdd + NDEV;
    size_t o_curad = o_rsad + NDEV;
    size_t o_ssdd  = o_curad + NDEV;          // int[262144]
    size_t o_ssad  = o_ssdd + EDD;            // int[32768]
    size_t o_smax  = o_ssad + EAD;
    size_t o_ssum  = o_smax + 32;
    size_t o_sargm = o_ssum + 32;

    float* out = (float*)d_out;
    float* out_hard   = out;                 // [8192][8]
    float* out_logits = out + 65536;         // [8192][32]
    float* out_soft   = out + 65536 + 262144;

    hipMemsetAsync((void*)(ws + o_zero), 0, (o_zend - o_zero) * sizeof(float), stream);
    repack_kernel<<<164, 256, 0, stream>>>(w2, ws + o_wpk, w1, ws + o_w1p,
                                           fcW, (uint4*)(ws + o_wfc),
                                           Wc, (uint4*)(ws + o_wcc));

    // graph prep
    degrees_kernel<<<EDD / 256, 256, 0, stream>>>(dd_src, dd_dst, da_src, da_dst, ad_src, ad_dst,
                                                  (int*)(ws + o_degddo), (int*)(ws + o_degddi),
                                                  (int*)(ws + o_degdao), (int*)(ws + o_degadi),
                                                  (int*)(ws + o_degsm));
    scan_kernel<<<2, 1024, 0, stream>>>((int*)(ws + o_degddi), (int*)(ws + o_rsdd), (int*)(ws + o_curdd),
                                        (int*)(ws + o_degadi), (int*)(ws + o_rsad), (int*)(ws + o_curad));
    reorder_kernel<<<EDD / 256, 256, 0, stream>>>(dd_src, dd_dst, (int*)(ws + o_curdd),
                                                  (int*)(ws + o_ssdd), EDD);
    reorder_kernel<<<EAD / 256, 256, 0, stream>>>(ad_src, ad_dst, (int*)(ws + o_curad),
                                                  (int*)(ws + o_ssad), EAD);

    // CSI encoder: persistent fused conv1+conv2+fc (1 block/CU, 8 groups each)
    convfc_kernel<<<256, 1024, 0, stream>>>(csi, ws + o_w1p, b1, ws + o_wpk, b2,
                                            (const uint4*)(ws + o_wfc), fcb, ws + o_emb);

    // device encoder (merge block 0 also does the AP encoder)
    fc16_kernel<<<NDEV / 16, 256, 0, stream>>>(ws + o_emb, (const uint4*)(ws + o_wcc),
                                               bc, ws + o_csif, 256);
    merge_kernel<<<NDEV / 4, 256, 0, stream>>>(device_pos, node_pk, ws + o_csif,
                                               Wp, bp, Wm, bm, (int*)(ws + o_degddo),
                                               ws + o_hdev, ws + o_xn,
                                               ap_pos, Wap, bap, (int*)(ws + o_degsm) + 8,
                                               ws + o_hap, ws + o_xnap);

    // layer 1 (fused gathers + da; fused combine + ha)
    gatherx_kernel<<<1280, 256, 0, stream>>>((int*)(ws + o_rsdd), (int*)(ws + o_degddi),
                                             (int*)(ws + o_ssdd), ws + o_xn, ws + o_aggdd,
                                             (int*)(ws + o_rsad), (int*)(ws + o_degadi),
                                             (int*)(ws + o_ssad), ws + o_xnap, ws + o_aggad,
                                             da_src, da_dst, ws + o_hdev,
                                             (int*)(ws + o_degdao), ws + o_aggda);
    combinex_kernel<<<2049, 256, 0, stream>>>(ws + o_aggdd, g1ddW, g1ddb,
                                              ws + o_aggad, g1adW, g1adb,
                                              (int*)(ws + o_degddo), ws + o_hd1, ws + o_xn,
                                              ws + o_aggda, (int*)(ws + o_degsm),
                                              g1daW, g1dab, (int*)(ws + o_degsm) + 8,
                                              ws + o_ha1, ws + o_xnap);

    // layer 2
    gatherx_kernel<<<1024, 256, 0, stream>>>((int*)(ws + o_rsdd), (int*)(ws + o_degddi),
                                             (int*)(ws + o_ssdd), ws + o_xn, ws + o_aggdd,
                                             (int*)(ws + o_rsad), (int*)(ws + o_degadi),
                                             (int*)(ws + o_ssad), ws + o_xnap, ws + o_aggad,
                                             da_src, da_dst, ws + o_hd1,
                                             (int*)(ws + o_degdao), ws + o_aggda);
    combinex_kernel<<<2048, 256, 0, stream>>>(ws + o_aggdd, g2ddW, g2ddb,
                                              ws + o_aggad, g2adW, g2adb,
                                              (int*)(ws + o_degddo), ws + o_hd2, nullptr,
                                              nullptr, nullptr, nullptr, nullptr,
                                              nullptr, nullptr, nullptr);

    head_kernel<<<NDEV / 4, 256, 0, stream>>>(ws + o_hd2, a1W, a1b, a2W, a2b, out_logits);

    softmax_stats_kernel<<<32, 1024, 0, stream>>>(out_logits, ws + o_smax,
                                                  (int*)(ws + o_sargm), ws + o_ssum);
    final_kernel<<<65536 / 256, 256, 0, stream>>>(out_logits, ws + o_smax,
                                                  (int*)(ws + o_sargm), ws + o_ssum,
                                                  out_hard, out_soft);
    (void)in_sizes; (void)n_in; (void)out_size; (void)ws_size;
}

// Round 12
// 429.971 us; speedup vs baseline: 1.3286x; 1.3286x over previous
//
#include <hip/hip_runtime.h>

#define NDEV 8192
#define NAP  4
#define NSAMP 32768
#define EDD 262144
#define EDA 32768
#define EAD 32768
#define KC 128
#define ASTR2 132

typedef float vf2 __attribute__((ext_vector_type(2)));
static __device__ __forceinline__ vf2 pk_fma(vf2 a, vf2 b, vf2 c) {
    return __builtin_elementwise_fma(a, b, c);
}

using sh8 = __attribute__((ext_vector_type(8))) short;     // 8 bf16 (4 VGPRs)
using f32x4 = __attribute__((ext_vector_type(4))) float;   // 16x16 MFMA acc
using f32x16 = __attribute__((ext_vector_type(16))) float; // 32x32 MFMA acc

static __device__ __forceinline__ unsigned short bf16_rtne(float f) {
    unsigned u = __float_as_uint(f);
    u += 0x7fffu + ((u >> 16) & 1u);
    return (unsigned short)(u >> 16);
}
static __device__ __forceinline__ float bf16f(unsigned short h) {
    return __uint_as_float(((unsigned)h) << 16);
}

// ---------------------------------------------------------------------------
// Repack:
//  - conv2 weights -> 32x32 MFMA B-frags (bf16 hi/lo), uint4[(tap*2+s)*64+l]
//  - conv1 weights -> w1p (unchanged)
//  - fcW (2048x64) -> 16x16 MFMA B-frags with K-PERMUTATION k' = pos*32+oc
//      (inverse: k_orig = (k'&31)*64 + (k'>>5)); matches convfc's c2h layout.
//  - Wc (256x64) -> 16x16 MFMA B-frags, UNPERMUTED (emb layout standard).
// ---------------------------------------------------------------------------
__global__ void repack_kernel(const float* __restrict__ w2, float* __restrict__ wpk,
                              const float* __restrict__ w1, float* __restrict__ w1p,
                              const float* __restrict__ fcW, uint4* __restrict__ wfc,
                              const float* __restrict__ Wc, uint4* __restrict__ wcc)
{
    int i = blockIdx.x * 256 + threadIdx.x;
    if (i < 1152) {
        int lane = i & 63, s = (i >> 6) & 1, tap = i >> 7;
        int oc = lane & 31, g = lane >> 5;
        unsigned int d[4];
        #pragma unroll
        for (int d4 = 0; d4 < 4; ++d4) {
            unsigned short u01[2];
            #pragma unroll
            for (int h = 0; h < 2; ++h) {
                int e = 2 * d4 + h;
                int ic = g * 8 + e;
                float v = w2[oc * 144 + ic * 9 + tap];
                unsigned short hi = bf16_rtne(v);
                u01[h] = (s == 0) ? hi : bf16_rtne(v - bf16f(hi));
            }
            d[d4] = (unsigned)u01[0] | ((unsigned)u01[1] << 16);
        }
        ((uint4*)wpk)[i] = make_uint4(d[0], d[1], d[2], d[3]);
    }
    int j = i - 4608;
    if (j >= 0 && j < 288) {
        int h = j & 1, v = j >> 1;       // v = r*8 + o2
        int o2 = v & 7, r = v >> 3;      // r = ic*9+k in [0,18)
        w1p[j] = w1[(2 * o2 + h) * 18 + r];
    }
    // fc weight fragments (k-permuted for convfc's c2h layout)
    int h1 = i - 5120;
    if (h1 >= 0 && h1 < 32768) {
        int s = h1 & 1, l = (h1 >> 1) & 63, nt = (h1 >> 7) & 3, kstep = h1 >> 9;
        unsigned int d[4];
        #pragma unroll
        for (int d4 = 0; d4 < 4; ++d4) {
            unsigned short u01[2];
            #pragma unroll
            for (int hh = 0; hh < 2; ++hh) {
                int e = 2 * d4 + hh;
                int kp = kstep * 32 + (l >> 4) * 8 + e;      // permuted k'
                int korig = (kp & 31) * 64 + (kp >> 5);      // oc*64 + pos
                int n = nt * 16 + (l & 15);
                float v = fcW[(long)korig * 64 + n];
                unsigned short hi = bf16_rtne(v);
                u01[hh] = (s == 0) ? hi : bf16_rtne(v - bf16f(hi));
            }
            d[d4] = (unsigned)u01[0] | ((unsigned)u01[1] << 16);
        }
        wfc[h1] = make_uint4(d[0], d[1], d[2], d[3]);
    }
    int h2 = i - 37888;
    if (h2 >= 0 && h2 < 4096) {
        int s = h2 & 1, l = (h2 >> 1) & 63, nt = (h2 >> 7) & 3, kstep = h2 >> 9;
        unsigned int d[4];
        #pragma unroll
        for (int d4 = 0; d4 < 4; ++d4) {
            unsigned short u01[2];
            #pragma unroll
            for (int hh = 0; hh < 2; ++hh) {
                int e = 2 * d4 + hh;
                int k = kstep * 32 + (l >> 4) * 8 + e;
                int n = nt * 16 + (l & 15);
                float v = Wc[(long)k * 64 + n];
                unsigned short hi = bf16_rtne(v);
                u01[hh] = (s == 0) ? hi : bf16_rtne(v - bf16f(hi));
            }
            d[d4] = (unsigned)u01[0] | ((unsigned)u01[1] << 16);
        }
        wcc[h2] = make_uint4(d[0], d[1], d[2], d[3]);
    }
}

// ---------------------------------------------------------------------------
// Fused CSI encoder, 1024-thread / 16-wave LAUNCH form (round-9 verified:
// 436 us wall, convfc 151 us, no spill traffic).  conv1: wave w = sample w;
// conv2: wave w = sample w, one barrier between all c1h reads and c2h
// writes; fc: wave w -> ks = w&7, nt in {(w>>3)*2, +1}.
// ---------------------------------------------------------------------------
#define C2STR 2052  /* c2h row stride in floats (2048 + 4 pad; %32==4) */
__global__ __launch_bounds__(1024) void convfc_kernel(
    const float* __restrict__ csi,
    const float* __restrict__ w1p, const float* __restrict__ b1,
    const float* __restrict__ wpk, const float* __restrict__ b2,
    const uint4* __restrict__ wfc, const float* __restrict__ fcb,
    float* __restrict__ emb)
{
    __shared__ __align__(16) char smem[135680];
    __shared__ float sw1p[288];
    __shared__ float sb1[16];
    __shared__ float sb2[32];
    __shared__ float sbF[64];
    float* inpad = (float*)smem;                              // [16][2][10][10]
    unsigned short* c1h = (unsigned short*)(smem + 12800);    // 16si x 4pl x 960 shorts
    float* c2h = (float*)smem;                                // [16][C2STR]
    float* red = (float*)smem;                                // [128][64] epilogue
    const int tid = threadIdx.x;
    const int lane = tid & 63;
    const int w = __builtin_amdgcn_readfirstlane(tid >> 6);   // wave 0..15

    for (int i = tid; i < 288; i += 1024) sw1p[i] = w1p[i];
    if (tid < 16) sb1[tid] = b1[tid];
    if (tid < 32) sb2[tid] = b2[tid];
    if (tid < 64) sbF[tid] = fcb[tid];
    {
        const uint4 z4 = make_uint4(0u, 0u, 0u, 0u);
        uint4* ip4 = (uint4*)inpad;
        for (int i = tid; i < 800; i += 1024) ip4[i] = z4;
        uint4* c14 = (uint4*)c1h;
        for (int i = tid; i < 7680; i += 1024) c14[i] = z4;   // exact c1h extent
    }
    __syncthreads();

    const long s0 = (long)blockIdx.x * 16;
    for (int i = tid; i < 2048; i += 1024) {
        int si = i >> 7, r = i & 127;
        int f = r >> 4, t = (r >> 1) & 7, c = r & 1;
        inpad[si * 200 + c * 100 + (f + 1) * 10 + (t + 1)] = csi[s0 * 128 + i];
    }
    __syncthreads();

    // ---- conv1: wave w = sample w, thread = (f1, t1), all 16 ocs ----
    {
        const int si1 = w;
        const int p1 = lane;
        const int f1 = p1 >> 3, t1 = p1 & 7;
        float inv[18];
        #pragma unroll
        for (int ic = 0; ic < 2; ++ic)
            #pragma unroll
            for (int df = 0; df < 3; ++df)
                #pragma unroll
                for (int dt = 0; dt < 3; ++dt)
                    inv[ic * 9 + df * 3 + dt] =
                        inpad[si1 * 200 + ic * 100 + (f1 + df) * 10 + (t1 + dt)];
        vf2 a1[8];
        #pragma unroll
        for (int o2 = 0; o2 < 8; ++o2) a1[o2] = (vf2){sb1[2 * o2], sb1[2 * o2 + 1]};
        const vf2* sw1v = (const vf2*)sw1p;
        #pragma unroll
        for (int r = 0; r < 18; ++r) {
            vf2 xv = {inv[r], inv[r]};
            #pragma unroll
            for (int o2 = 0; o2 < 8; ++o2)
                a1[o2] = pk_fma(xv, sw1v[r * 8 + o2], a1[o2]);
        }
        float v[16];
        #pragma unroll
        for (int o2 = 0; o2 < 8; ++o2) {
            v[2 * o2]     = fmaxf(a1[o2].x, 0.f);
            v[2 * o2 + 1] = fmaxf(a1[o2].y, 0.f);
        }
        const int cell = ((f1 + 1) * 12 + (t1 + 1)) * 8;
        #pragma unroll
        for (int g = 0; g < 2; ++g) {
            unsigned int hd[4], ld[4];
            #pragma unroll
            for (int d = 0; d < 4; ++d) {
                float x0 = v[g * 8 + 2 * d], x1 = v[g * 8 + 2 * d + 1];
                unsigned short h0 = bf16_rtne(x0), h1 = bf16_rtne(x1);
                unsigned short l0 = bf16_rtne(x0 - bf16f(h0));
                unsigned short l1 = bf16_rtne(x1 - bf16f(h1));
                hd[d] = (unsigned)h0 | ((unsigned)h1 << 16);
                ld[d] = (unsigned)l0 | ((unsigned)l1 << 16);
            }
            *(uint4*)&c1h[(si1 * 4 + g) * 960 + cell]     = make_uint4(hd[0], hd[1], hd[2], hd[3]);
            *(uint4*)&c1h[(si1 * 4 + 2 + g) * 960 + cell] = make_uint4(ld[0], ld[1], ld[2], ld[3]);
        }
    }

    // preload conv2 B fragments (block-invariant) while waiting
    sh8 Bh[9], Bl[9];
    {
        const sh8* bfp = (const sh8*)wpk;
        #pragma unroll
        for (int tap = 0; tap < 9; ++tap) {
            Bh[tap] = bfp[(tap * 2 + 0) * 64 + lane];
            Bl[tap] = bfp[(tap * 2 + 1) * 64 + lane];
        }
    }
    __syncthreads();

    // ---- conv2: wave w = sample w (single step) ----
    const int rr = lane & 31, g = lane >> 5;
    const float bias2 = sb2[rr];
    const int p0f = rr >> 3, pt = rr & 7;
    const int p1f = 4 + p0f;
    {
        const int s = w;
        f32x16 acc0, acc1;
        #pragma unroll
        for (int u = 0; u < 16; ++u) { acc0[u] = bias2; acc1[u] = bias2; }
        const int hb = (s * 4 + g) * 960;
        const int lb = (s * 4 + 2 + g) * 960;
        #pragma unroll
        for (int df = 0; df < 3; ++df) {
            #pragma unroll
            for (int dt = 0; dt < 3; ++dt) {
                const int tap = df * 3 + dt;
                const int c0 = ((p0f + df) * 12 + (pt + dt)) * 8;
                const int c1i = ((p1f + df) * 12 + (pt + dt)) * 8;
                sh8 Ah0 = *(const sh8*)&c1h[hb + c0];
                sh8 Al0 = *(const sh8*)&c1h[lb + c0];
                sh8 Ah1 = *(const sh8*)&c1h[hb + c1i];
                sh8 Al1 = *(const sh8*)&c1h[lb + c1i];
                acc0 = __builtin_amdgcn_mfma_f32_32x32x16_bf16(Ah0, Bh[tap], acc0, 0, 0, 0);
                acc1 = __builtin_amdgcn_mfma_f32_32x32x16_bf16(Ah1, Bh[tap], acc1, 0, 0, 0);
                acc0 = __builtin_amdgcn_mfma_f32_32x32x16_bf16(Ah0, Bl[tap], acc0, 0, 0, 0);
                acc1 = __builtin_amdgcn_mfma_f32_32x32x16_bf16(Ah1, Bl[tap], acc1, 0, 0, 0);
                acc0 = __builtin_amdgcn_mfma_f32_32x32x16_bf16(Al0, Bh[tap], acc0, 0, 0, 0);
                acc1 = __builtin_amdgcn_mfma_f32_32x32x16_bf16(Al1, Bh[tap], acc1, 0, 0, 0);
            }
        }
        __syncthreads();   // ALL c1h reads complete before ANY c2h write
        float* crow = c2h + (size_t)s * C2STR;
        #pragma unroll
        for (int i = 0; i < 16; ++i) {
            const int pos = (i & 3) + 8 * (i >> 2) + 4 * g;
            crow[pos * 32 + rr]        = fmaxf(acc0[i], 0.f);
            crow[(pos + 32) * 32 + rr] = fmaxf(acc1[i], 0.f);
        }
    }
    __syncthreads();

    // ---- fc stage: wave w -> ks = w&7, nt in {ntb, ntb+1}, M=16 samples ----
    const int ks = w & 7;
    const int ntb = (w >> 3) * 2;    // 0 or 2
    const int mrow = lane & 15;
    const int g2 = lane >> 4;
    f32x4 acc[2];
    #pragma unroll
    for (int ni = 0; ni < 2; ++ni) acc[ni] = (f32x4){0.f, 0.f, 0.f, 0.f};
    #pragma unroll
    for (int t = 0; t < 8; ++t) {
        const int kstep = ks * 8 + t;
        const uint4* bp = wfc + (size_t)kstep * 512 + lane * 2;
        uint4 bh0 = bp[ntb * 128],       bl0 = bp[ntb * 128 + 1];
        uint4 bh1 = bp[(ntb + 1) * 128], bl1 = bp[(ntb + 1) * 128 + 1];
        const float4 a0 = *(const float4*)&c2h[mrow * C2STR + kstep * 32 + g2 * 8];
        const float4 a1 = *(const float4*)&c2h[mrow * C2STR + kstep * 32 + g2 * 8 + 4];
        float av[8] = {a0.x, a0.y, a0.z, a0.w, a1.x, a1.y, a1.z, a1.w};
        unsigned short hs[8], lss[8];
        #pragma unroll
        for (int e = 0; e < 8; ++e) {
            hs[e] = bf16_rtne(av[e]);
            lss[e] = bf16_rtne(av[e] - bf16f(hs[e]));
        }
        sh8 Ah = {(short)hs[0], (short)hs[1], (short)hs[2], (short)hs[3],
                  (short)hs[4], (short)hs[5], (short)hs[6], (short)hs[7]};
        sh8 Al = {(short)lss[0], (short)lss[1], (short)lss[2], (short)lss[3],
                  (short)lss[4], (short)lss[5], (short)lss[6], (short)lss[7]};
        acc[0] = __builtin_amdgcn_mfma_f32_16x16x32_bf16(Ah, *(const sh8*)&bh0, acc[0], 0, 0, 0);
        acc[0] = __builtin_amdgcn_mfma_f32_16x16x32_bf16(Ah, *(const sh8*)&bl0, acc[0], 0, 0, 0);
        acc[0] = __builtin_amdgcn_mfma_f32_16x16x32_bf16(Al, *(const sh8*)&bh0, acc[0], 0, 0, 0);
        acc[1] = __builtin_amdgcn_mfma_f32_16x16x32_bf16(Ah, *(const sh8*)&bh1, acc[1], 0, 0, 0);
        acc[1] = __builtin_amdgcn_mfma_f32_16x16x32_bf16(Ah, *(const sh8*)&bl1, acc[1], 0, 0, 0);
        acc[1] = __builtin_amdgcn_mfma_f32_16x16x32_bf16(Al, *(const sh8*)&bh1, acc[1], 0, 0, 0);
    }
    __syncthreads();   // c2h dead; red aliases it
    #pragma unroll
    for (int ni = 0; ni < 2; ++ni) {
        const int nt = ntb + ni;
        #pragma unroll
        for (int r = 0; r < 4; ++r)
            red[(ks * 16 + g2 * 4 + r) * 64 + nt * 16 + mrow] = acc[ni][r];
    }
    __syncthreads();
    if (tid < 256) {
        const int m = tid >> 4, oq = tid & 15;
        float4 sum;
        sum.x = sbF[oq * 4 + 0]; sum.y = sbF[oq * 4 + 1];
        sum.z = sbF[oq * 4 + 2]; sum.w = sbF[oq * 4 + 3];
        #pragma unroll
        for (int jq = 0; jq < 8; ++jq) {
            float4 rv = *(float4*)&red[(jq * 16 + m) * 64 + oq * 4];
            sum.x += rv.x; sum.y += rv.y; sum.z += rv.z; sum.w += rv.w;
        }
        float4 o4;
        o4.x = fmaxf(sum.x, 0.f); o4.y = fmaxf(sum.y, 0.f);
        o4.z = fmaxf(sum.z, 0.f); o4.w = fmaxf(sum.w, 0.f);
        *(float4*)&emb[(s0 + m) * 64 + oq * 4] = o4;
    }
}

// ---------------------------------------------------------------------------
// fc16 via 16x16x32 bf16 MFMA (round-5 proven form) — used for Wc stage.
// ---------------------------------------------------------------------------
__global__ __launch_bounds__(256) void fc16_kernel(
    const float* __restrict__ A, const uint4* __restrict__ Wfrag,
    const float* __restrict__ bias, float* __restrict__ out, int K)
{
    __shared__ __align__(16) float smem[4224];
    float* As = smem;
    const int tid = threadIdx.x;
    const long m0g = (long)blockIdx.x * 16;
    const int ks = tid >> 6;
    const int lane = tid & 63;
    const int mrow = lane & 15;
    const int g = lane >> 4;

    f32x4 acc[4];
    #pragma unroll
    for (int nt = 0; nt < 4; ++nt) acc[nt] = (f32x4){0.f, 0.f, 0.f, 0.f};

    for (int kc = 0; kc < K; kc += KC) {
        __syncthreads();
        #pragma unroll
        for (int i = 0; i < 2; ++i) {
            int idx = tid + i * 256;
            int m = idx >> 5, kq = idx & 31;
            float4 v = *(const float4*)&A[(m0g + m) * K + kc + kq * 4];
            *(float4*)&As[m * ASTR2 + kq * 4] = v;
        }
        __syncthreads();
        const int kstep = (kc >> 5) + ks;
        const uint4* bp = Wfrag + (size_t)kstep * 512 + lane * 2;
        uint4 bh0 = bp[0],   bl0 = bp[1];
        uint4 bh1 = bp[128], bl1 = bp[129];
        uint4 bh2 = bp[256], bl2 = bp[257];
        uint4 bh3 = bp[384], bl3 = bp[385];
        const float4 a0 = *(const float4*)&As[mrow * ASTR2 + ks * 32 + g * 8];
        const float4 a1 = *(const float4*)&As[mrow * ASTR2 + ks * 32 + g * 8 + 4];
        float av[8] = {a0.x, a0.y, a0.z, a0.w, a1.x, a1.y, a1.z, a1.w};
        unsigned short hs[8], lss[8];
        #pragma unroll
        for (int e = 0; e < 8; ++e) {
            hs[e] = bf16_rtne(av[e]);
            lss[e] = bf16_rtne(av[e] - bf16f(hs[e]));
        }
        sh8 Ah = {(short)hs[0], (short)hs[1], (short)hs[2], (short)hs[3],
                  (short)hs[4], (short)hs[5], (short)hs[6], (short)hs[7]};
        sh8 Al = {(short)lss[0], (short)lss[1], (short)lss[2], (short)lss[3],
                  (short)lss[4], (short)lss[5], (short)lss[6], (short)lss[7]};
        #define FCMM(ntv, bhv, blv) \
            acc[ntv] = __builtin_amdgcn_mfma_f32_16x16x32_bf16(Ah, *(const sh8*)&(bhv), acc[ntv], 0, 0, 0); \
            acc[ntv] = __builtin_amdgcn_mfma_f32_16x16x32_bf16(Ah, *(const sh8*)&(blv), acc[ntv], 0, 0, 0); \
            acc[ntv] = __builtin_amdgcn_mfma_f32_16x16x32_bf16(Al, *(const sh8*)&(bhv), acc[ntv], 0, 0, 0);
        FCMM(0, bh0, bl0)
        FCMM(1, bh1, bl1)
        FCMM(2, bh2, bl2)
        FCMM(3, bh3, bl3)
        #undef FCMM
    }
    __syncthreads();
    float* red = smem;
    #pragma unroll
    for (int nt = 0; nt < 4; ++nt)
        #pragma unroll
        for (int r = 0; r < 4; ++r)
            red[(ks * 16 + g * 4 + r) * 64 + nt * 16 + mrow] = acc[nt][r];
    __syncthreads();
    {
        int m = tid >> 4, oq = tid & 15;
        float4 r0 = *(float4*)&red[(0 * 16 + m) * 64 + oq * 4];
        float4 r1 = *(float4*)&red[(1 * 16 + m) * 64 + oq * 4];
        float4 r2 = *(float4*)&red[(2 * 16 + m) * 64 + oq * 4];
        float4 r3 = *(float4*)&red[(3 * 16 + m) * 64 + oq * 4];
        const float4 b4 = *(const float4*)&bias[oq * 4];
        float4 o4;
        o4.x = fmaxf(r0.x + r1.x + r2.x + r3.x + b4.x, 0.f);
        o4.y = fmaxf(r0.y + r1.y + r2.y + r3.y + b4.y, 0.f);
        o4.z = fmaxf(r0.z + r1.z + r2.z + r3.z + b4.z, 0.f);
        o4.w = fmaxf(r0.w + r1.w + r2.w + r3.w + b4.w, 0.f);
        *(float4*)&out[(m0g + m) * 64 + oq * 4] = o4;
    }
}

// ---------------------------------------------------------------------------
// Device merge + fused xnorm; block 0 additionally computes the AP encoder.
// ---------------------------------------------------------------------------
__global__ __launch_bounds__(256) void merge_kernel(
    const float* __restrict__ dpos, const int* __restrict__ pkts,
    const float* __restrict__ csif,
    const float* __restrict__ Wp, const float* __restrict__ bp,
    const float* __restrict__ Wm, const float* __restrict__ bm,
    const int* __restrict__ degout,
    float* __restrict__ hdev, float* __restrict__ xn,
    const float* __restrict__ appos, const float* __restrict__ Wap,
    const float* __restrict__ bap, const int* __restrict__ degapo,
    float* __restrict__ hap, float* __restrict__ xnap)
{
    __shared__ float sWm[80][64];
    __shared__ float spos[4][16];
    __shared__ float scf[4][64];
    const int tid = threadIdx.x;
    for (int i = tid; i < 5120; i += 256) sWm[i >> 6][i & 63] = Wm[i];
    const int n0 = blockIdx.x * 4;
    (&scf[0][0])[tid] = csif[(long)n0 * 64 + tid];
    if (tid < 64) {
        int dl = tid >> 4, o = tid & 15;
        int d = n0 + dl;
        float px = dpos[d * 2], py = dpos[d * 2 + 1], pk = (float)pkts[d];
        float v = bp[o] + px * Wp[o] + py * Wp[16 + o] + pk * Wp[32 + o];
        spos[dl][o] = fmaxf(v, 0.f);
    }
    __syncthreads();
    const int o = tid & 63, dl = tid >> 6;
    float h = bm[o];
    #pragma unroll
    for (int j = 0; j < 16; ++j) h += spos[dl][j] * sWm[j][o];
    #pragma unroll 8
    for (int j = 0; j < 64; ++j) h += scf[dl][j] * sWm[16 + j][o];
    h = fmaxf(h, 0.f);
    const long idx = (long)(n0 + dl) * 64 + o;
    hdev[idx] = h;
    xn[idx] = h * rsqrtf(fmaxf((float)degout[n0 + dl], 1.f));
    if (blockIdx.x == 0) {
        int a = tid >> 6, oo = tid & 63;
        float v = fmaxf(bap[oo] + appos[a * 2] * Wap[oo] + appos[a * 2 + 1] * Wap[64 + oo], 0.f);
        hap[tid] = v;
        xnap[tid] = v * rsqrtf(fmaxf((float)degapo[a], 1.f));
    }
}

// ---------------------------------------------------------------------------
__global__ __launch_bounds__(256) void degrees_kernel(
    const int* __restrict__ dd_src, const int* __restrict__ dd_dst,
    const int* __restrict__ da_src, const int* __restrict__ da_dst,
    const int* __restrict__ ad_src, const int* __restrict__ ad_dst,
    int* deg_dd_out, int* deg_dd_in, int* deg_da_out, int* deg_ad_in, int* deg_small)
{
    __shared__ int s4[16];
    const int tid = threadIdx.x;
    if (tid < 16) s4[tid] = 0;
    __syncthreads();
    const int gid = blockIdx.x * 256 + tid;
    atomicAdd(&deg_dd_out[dd_src[gid]], 1);
    atomicAdd(&deg_dd_in[dd_dst[gid]], 1);
    if (gid < EDA) {
        atomicAdd(&deg_da_out[da_src[gid]], 1);
        atomicAdd(&s4[da_dst[gid]], 1);
        atomicAdd(&s4[8 + ad_src[gid]], 1);
        atomicAdd(&deg_ad_in[ad_dst[gid]], 1);
    }
    __syncthreads();
    if (tid < 16 && s4[tid] != 0) atomicAdd(&deg_small[tid], s4[tid]);
}

__global__ __launch_bounds__(1024) void scan_kernel(
    const int* __restrict__ degA, int* rsA, int* curA,
    const int* __restrict__ degB, int* rsB, int* curB)
{
    const int* deg = blockIdx.x ? degB : degA;
    int* rs = blockIdx.x ? rsB : rsA;
    int* cur = blockIdx.x ? curB : curA;
    __shared__ int sd[1024];
    const int tid = threadIdx.x;
    const int base = tid * 8;
    int v[8]; int s = 0;
    #pragma unroll
    for (int j = 0; j < 8; ++j) { v[j] = deg[base + j]; s += v[j]; }
    sd[tid] = s;
    __syncthreads();
    for (int off = 1; off < 1024; off <<= 1) {
        int t = (tid >= off) ? sd[tid - off] : 0;
        __syncthreads();
        sd[tid] += t;
        __syncthreads();
    }
    int ex = sd[tid] - s;
    #pragma unroll
    for (int j = 0; j < 8; ++j) { rs[base + j] = ex; cur[base + j] = ex; ex += v[j]; }
}

__global__ __launch_bounds__(256) void reorder_kernel(
    const int* __restrict__ src, const int* __restrict__ dst,
    int* __restrict__ cursor, int* __restrict__ ssrc, int nE)
{
    int e = blockIdx.x * 256 + threadIdx.x;
    if (e < nE) {
        int pos = atomicAdd(&cursor[dst[e]], 1);
        ssrc[pos] = src[e];
    }
}

// ---------------------------------------------------------------------------
// Fused gather launch: blocks [0,512) dd (16 devices/block), [512,1024) ad,
// [1024,1280) da LDS-reduce (layer 1 only).  (round-6 proven form)
// ---------------------------------------------------------------------------
__global__ __launch_bounds__(256) void gatherx_kernel(
    const int* __restrict__ rsdd, const int* __restrict__ degddi,
    const int* __restrict__ ssdd, const float* __restrict__ xn, float* __restrict__ aggdd,
    const int* __restrict__ rsad, const int* __restrict__ degadi,
    const int* __restrict__ ssad, const float* __restrict__ xnap, float* __restrict__ aggad,
    const int* __restrict__ da_src, const int* __restrict__ da_dst,
    const float* __restrict__ hdev, const int* __restrict__ degdao,
    float* __restrict__ aggda)
{
    __shared__ float sacc[4][64];
    const int b = blockIdx.x;
    const int tid = threadIdx.x;
    if (b < 1024) {
        const bool isdd = b < 512;
        const int lane = tid & 63;
        const int gbase = lane & 48;
        const int lg = lane & 15;
        const int fq = lg * 4;
        const int d = (isdd ? b : b - 512) * 16 + (tid >> 4);
        const int* rs = isdd ? rsdd : rsad;
        const int* dg = isdd ? degddi : degadi;
        const int* ss = isdd ? ssdd : ssad;
        const float* x = isdd ? xn : xnap;
        float* agg = isdd ? aggdd : aggad;
        const int start = rs[d], len = dg[d];
        float ax = 0.f, ay = 0.f, az = 0.f, aw = 0.f;
        for (int j = 0; j < len; j += 16) {
            const int rem = min(16, len - j);
            const int myidx = ss[start + j + min(lg, rem - 1)];
            float4 v[16];
            #pragma unroll
            for (int k = 0; k < 16; ++k) {
                const int sk = __shfl(myidx, gbase + min(k, rem - 1), 64);
                v[k] = *(const float4*)&x[(long)sk * 64 + fq];
            }
            #pragma unroll
            for (int k = 0; k < 16; ++k) {
                const float m = (k < rem) ? 1.f : 0.f;
                ax += m * v[k].x; ay += m * v[k].y;
                az += m * v[k].z; aw += m * v[k].w;
            }
        }
        const float sc = rsqrtf(fmaxf((float)len, 1.f));
        float4 o;
        o.x = ax * sc; o.y = ay * sc; o.z = az * sc; o.w = aw * sc;
        *(float4*)&agg[(long)d * 64 + fq] = o;
    } else {
        (&sacc[0][0])[tid] = 0.f;
        __syncthreads();
        const int f = tid & 63;
        const int base = (b - 1024) * 128;
        for (int e = base + (tid >> 6); e < base + 128; e += 4) {
            int s = da_src[e], d = da_dst[e];
            float sc = rsqrtf(fmaxf((float)degdao[s], 1.f));
            atomicAdd(&sacc[d][f], hdev[(long)s * 64 + f] * sc);
        }
        __syncthreads();
        float v = (&sacc[0][0])[tid];
        if (v != 0.f) atomicAdd(&aggda[tid], v);
    }
}

// ---------------------------------------------------------------------------
// Fused combine: blocks [0,2048) hd (two relations); block 2048 (layer 1) ha.
// ---------------------------------------------------------------------------
__global__ __launch_bounds__(256) void combinex_kernel(
    const float* __restrict__ agg1, const float* __restrict__ W1, const float* __restrict__ b1,
    const float* __restrict__ agg2, const float* __restrict__ W2, const float* __restrict__ b2,
    const int* __restrict__ degout, float* __restrict__ out, float* __restrict__ xnout,
    const float* __restrict__ aggda, const int* __restrict__ degdai,
    const float* __restrict__ Wda, const float* __restrict__ bda,
    const int* __restrict__ degapo, float* __restrict__ ha_out, float* __restrict__ ha_xn)
{
    __shared__ float sW1[64][64];
    __shared__ float sW2[64][64];
    __shared__ float sa1[4][64];
    __shared__ float sa2[4][64];
    const int tid = threadIdx.x;
    if (blockIdx.x < 2048) {
        for (int i = tid; i < 4096; i += 256) { sW1[i >> 6][i & 63] = W1[i]; sW2[i >> 6][i & 63] = W2[i]; }
        const int n0 = blockIdx.x * 4;
        (&sa1[0][0])[tid] = agg1[(long)n0 * 64 + tid];
        (&sa2[0][0])[tid] = agg2[(long)n0 * 64 + tid];
        __syncthreads();
        const int o = tid & 63, dl = tid >> 6;
        float acc1 = 0.f, acc2 = 0.f;
        #pragma unroll 8
        for (int k = 0; k < 64; ++k) {
            acc1 += sa1[dl][k] * sW1[k][o];
            acc2 += sa2[dl][k] * sW2[k][o];
        }
        float h = fmaxf(acc1 + acc2 + b1[o] + b2[o], 0.f);
        const long idx = (long)(n0 + dl) * 64 + o;
        out[idx] = h;
        if (xnout) xnout[idx] = h * rsqrtf(fmaxf((float)degout[n0 + dl], 1.f));
    } else {
        const int o = tid & 63, a = tid >> 6;
        float acc = 0.f;
        for (int k = 0; k < 64; ++k) acc += aggda[a * 64 + k] * Wda[k * 64 + o];
        float r = rsqrtf(fmaxf((float)degdai[a], 1.f));
        float h = fmaxf(acc * r + bda[o], 0.f);
        ha_out[tid] = h;
        ha_xn[tid] = h * rsqrtf(fmaxf((float)degapo[a], 1.f));
    }
}

// ---------------------------------------------------------------------------
__global__ __launch_bounds__(256) void head_kernel(
    const float* __restrict__ hd2,
    const float* __restrict__ W1, const float* __restrict__ b1,
    const float* __restrict__ W2, const float* __restrict__ b2,
    float* __restrict__ logits_out)
{
    __shared__ float sW1[64][64];
    __shared__ float sW2[64][32];
    __shared__ float sh[4][64];
    __shared__ float st[4][64];
    const int tid = threadIdx.x;
    for (int i = tid; i < 4096; i += 256) sW1[i >> 6][i & 63] = W1[i];
    for (int i = tid; i < 2048; i += 256) sW2[i >> 5][i & 31] = W2[i];
    const int n0 = blockIdx.x * 4;
    (&sh[0][0])[tid] = hd2[(long)n0 * 64 + tid];
    __syncthreads();
    const int o = tid & 63, dl = tid >> 6;
    float acc = b1[o];
    #pragma unroll 8
    for (int k = 0; k < 64; ++k) acc += sh[dl][k] * sW1[k][o];
    st[dl][o] = fmaxf(acc, 0.f);
    __syncthreads();
    if (tid < 128) {
        int j = tid & 31, d2 = tid >> 5;
        float a2 = b2[j];
        #pragma unroll 8
        for (int k = 0; k < 64; ++k) a2 += st[d2][k] * sW2[k][j];
        logits_out[(long)(n0 + d2) * 32 + j] = a2;
    }
}

// ---------------------------------------------------------------------------
__global__ __launch_bounds__(1024) void softmax_stats_kernel(
    const float* __restrict__ logits,
    float* __restrict__ smax, int* __restrict__ sargm, float* __restrict__ ssum)
{
    __shared__ float smx[1024];
    __shared__ int sid[1024];
    __shared__ float ssm[1024];
    const int j = blockIdx.x;
    const int tid = threadIdx.x;
    float best = -__builtin_inff(); int bid = 0x7fffffff;
    for (int n = tid; n < NDEV; n += 1024) {
        float v = logits[n * 32 + j];
        if (v > best) { best = v; bid = n; }
    }
    smx[tid] = best; sid[tid] = bid;
    __syncthreads();
    for (int s = 512; s > 0; s >>= 1) {
        if (tid < s) {
            float v2 = smx[tid + s]; int i2 = sid[tid + s];
            if (v2 > smx[tid] || (v2 == smx[tid] && i2 < sid[tid])) { smx[tid] = v2; sid[tid] = i2; }
        }
        __syncthreads();
    }
    const float mx = smx[0];
    float part = 0.f;
    for (int n = tid; n < NDEV; n += 1024) part += expf(logits[n * 32 + j] - mx);
    ssm[tid] = part;
    __syncthreads();
    for (int s = 512; s > 0; s >>= 1) {
        if (tid < s) ssm[tid] += ssm[tid + s];
        __syncthreads();
    }
    if (tid == 0) { smax[j] = mx; sargm[j] = sid[0]; ssum[j] = ssm[0]; }
}

__global__ __launch_bounds__(256) void final_kernel(
    const float* __restrict__ logits, const float* __restrict__ smax,
    const int* __restrict__ sargm, const float* __restrict__ ssum,
    float* __restrict__ hard, float* __restrict__ soft)
{
    const int gid = blockIdx.x * 256 + threadIdx.x;
    const int n = gid >> 3, t = gid & 7;
    float s = 0.f; int h = 0;
    #pragma unroll
    for (int a = 0; a < 4; ++a) {
        int j = t * 4 + a;
        s += expf(logits[n * 32 + j] - smax[j]) / ssum[j];
        h |= (sargm[j] == n) ? 1 : 0;
    }
    hard[gid] = (float)h;
    soft[gid] = s;
}

// ---------------------------------------------------------------------------
extern "C" void kernel_launch(void* const* d_in, const int* in_sizes, int n_in,
                              void* d_out, int out_size, void* d_ws, size_t ws_size,
                              hipStream_t stream)
{
    const float* device_pos = (const float*)d_in[0];
    const float* ap_pos     = (const float*)d_in[1];
    const float* csi        = (const float*)d_in[2];
    const int*   node_pk    = (const int*)d_in[3];
    const int* dd_src = (const int*)d_in[4];
    const int* dd_dst = (const int*)d_in[5];
    const int* da_src = (const int*)d_in[6];
    const int* da_dst = (const int*)d_in[7];
    const int* ad_src = (const int*)d_in[8];
    const int* ad_dst = (const int*)d_in[9];
    const float* w1  = (const float*)d_in[10]; const float* b1  = (const float*)d_in[11];
    const float* w2  = (const float*)d_in[12]; const float* b2  = (const float*)d_in[13];
    const float* fcW = (const float*)d_in[14]; const float* fcb = (const float*)d_in[15];
    const float* Wp  = (const float*)d_in[16]; const float* bp  = (const float*)d_in[17];
    const float* Wc  = (const float*)d_in[18]; const float* bc  = (const float*)d_in[19];
    const float* Wm  = (const float*)d_in[20]; const float* bm  = (const float*)d_in[21];
    const float* Wap = (const float*)d_in[22]; const float* bap = (const float*)d_in[23];
    const float* g1ddW = (const float*)d_in[24]; const float* g1ddb = (const float*)d_in[25];
    const float* g1daW = (const float*)d_in[26]; const float* g1dab = (const float*)d_in[27];
    const float* g1adW = (const float*)d_in[28]; const float* g1adb = (const float*)d_in[29];
    const float* g2ddW = (const float*)d_in[30]; const float* g2ddb = (const float*)d_in[31];
    const float* g2adW = (const float*)d_in[34]; const float* g2adb = (const float*)d_in[35];
    const float* a1W = (const float*)d_in[36]; const float* a1b = (const float*)d_in[37];
    const float* a2W = (const float*)d_in[38]; const float* a2b = (const float*)d_in[39];

    float* ws = (float*)d_ws;
    size_t o_emb   = 0;                               // 2,097,152
    size_t o_csif  = o_emb + (size_t)NSAMP * 64;
    size_t o_hdev  = o_csif + (size_t)NDEV * 64;
    size_t o_hap   = o_hdev + (size_t)NDEV * 64;      // 256
    size_t o_hd1   = o_hap + 256;
    size_t o_ha1   = o_hd1 + (size_t)NDEV * 64;       // 256
    size_t o_hd2   = o_ha1 + 256;
    size_t o_aggdd = o_hd2 + (size_t)NDEV * 64;
    size_t o_aggad = o_aggdd + (size_t)NDEV * 64;
    size_t o_xn    = o_aggad + (size_t)NDEV * 64;
    size_t o_xnap  = o_xn + (size_t)NDEV * 64;        // 256
    size_t o_wpk   = o_xnap + 256;                    // 4608 (conv MFMA B-frags)
    size_t o_w1p   = o_wpk + 4608;                    // 288
    size_t o_wfc   = o_w1p + 288;                     // 131072 (fcW MFMA frags, permuted)
    size_t o_wcc   = o_wfc + 131072;                  // 16384 (Wc MFMA frags)
    // zero region
    size_t o_zero  = o_wcc + 16384;
    size_t o_degddo = o_zero;
    size_t o_degddi = o_degddo + NDEV;
    size_t o_degdao = o_degddi + NDEV;
    size_t o_degadi = o_degdao + NDEV;
    size_t o_degsm  = o_degadi + NDEV;        // int[16]
    size_t o_aggda  = o_degsm + 16;           // float[256]
    size_t o_zend   = o_aggda + 256;
    // non-zeroed
    size_t o_rsdd  = o_zend;
    size_t o_curdd = o_rsdd + NDEV;
    size_t o_rsad  = o_curdd + NDEV;
    size_t o_curad = o_rsad + NDEV;
    size_t o_ssdd  = o_curad + NDEV;          // int[262144]
    size_t o_ssad  = o_ssdd + EDD;            // int[32768]
    size_t o_smax  = o_ssad + EAD;
    size_t o_ssum  = o_smax + 32;
    size_t o_sargm = o_ssum + 32;

    float* out = (float*)d_out;
    float* out_hard   = out;                 // [8192][8]
    float* out_logits = out + 65536;         // [8192][32]
    float* out_soft   = out + 65536 + 262144;

    hipMemsetAsync((void*)(ws + o_zero), 0, (o_zend - o_zero) * sizeof(float), stream);
    repack_kernel<<<164, 256, 0, stream>>>(w2, ws + o_wpk, w1, ws + o_w1p,
                                           fcW, (uint4*)(ws + o_wfc),
                                           Wc, (uint4*)(ws + o_wcc));

    // graph prep
    degrees_kernel<<<EDD / 256, 256, 0, stream>>>(dd_src, dd_dst, da_src, da_dst, ad_src, ad_dst,
                                                  (int*)(ws + o_degddo), (int*)(ws + o_degddi),
                                                  (int*)(ws + o_degdao), (int*)(ws + o_degadi),
                                                  (int*)(ws + o_degsm));
    scan_kernel<<<2, 1024, 0, stream>>>((int*)(ws + o_degddi), (int*)(ws + o_rsdd), (int*)(ws + o_curdd),
                                        (int*)(ws + o_degadi), (int*)(ws + o_rsad), (int*)(ws + o_curad));
    reorder_kernel<<<EDD / 256, 256, 0, stream>>>(dd_src, dd_dst, (int*)(ws + o_curdd),
                                                  (int*)(ws + o_ssdd), EDD);
    reorder_kernel<<<EAD / 256, 256, 0, stream>>>(ad_src, ad_dst, (int*)(ws + o_curad),
                                                  (int*)(ws + o_ssad), EAD);

    // CSI encoder: fused conv1+conv2+fc (c2 never touches HBM)
    convfc_kernel<<<NSAMP / 16, 1024, 0, stream>>>(csi, ws + o_w1p, b1, ws + o_wpk, b2,
                                                   (const uint4*)(ws + o_wfc), fcb, ws + o_emb);

    // device encoder (merge block 0 also does the AP encoder)
    fc16_kernel<<<NDEV / 16, 256, 0, stream>>>(ws + o_emb, (const uint4*)(ws + o_wcc),
                                               bc, ws + o_csif, 256);
    merge_kernel<<<NDEV / 4, 256, 0, stream>>>(device_pos, node_pk, ws + o_csif,
                                               Wp, bp, Wm, bm, (int*)(ws + o_degddo),
                                               ws + o_hdev, ws + o_xn,
                                               ap_pos, Wap, bap, (int*)(ws + o_degsm) + 8,
                                               ws + o_hap, ws + o_xnap);

    // layer 1 (fused gathers + da; fused combine + ha)
    gatherx_kernel<<<1280, 256, 0, stream>>>((int*)(ws + o_rsdd), (int*)(ws + o_degddi),
                                             (int*)(ws + o_ssdd), ws + o_xn, ws + o_aggdd,
                                             (int*)(ws + o_rsad), (int*)(ws + o_degadi),
                                             (int*)(ws + o_ssad), ws + o_xnap, ws + o_aggad,
                                             da_src, da_dst, ws + o_hdev,
                                             (int*)(ws + o_degdao), ws + o_aggda);
    combinex_kernel<<<2049, 256, 0, stream>>>(ws + o_aggdd, g1ddW, g1ddb,
                                              ws + o_aggad, g1adW, g1adb,
                                              (int*)(ws + o_degddo), ws + o_hd1, ws + o_xn,
                                              ws + o_aggda, (int*)(ws + o_degsm),
                                              g1daW, g1dab, (int*)(ws + o_degsm) + 8,
                                              ws + o_ha1, ws + o_xnap);

    // layer 2
    gatherx_kernel<<<1024, 256, 0, stream>>>((int*)(ws + o_rsdd), (int*)(ws + o_degddi),
                                             (int*)(ws + o_ssdd), ws + o_xn, ws + o_aggdd,
                                             (int*)(ws + o_rsad), (int*)(ws + o_degadi),
                                             (int*)(ws + o_ssad), ws + o_xnap, ws + o_aggad,
                                             da_src, da_dst, ws + o_hd1,
                                             (int*)(ws + o_degdao), ws + o_aggda);
    combinex_kernel<<<2048, 256, 0, stream>>>(ws + o_aggdd, g2ddW, g2ddb,
                                              ws + o_aggad, g2adW, g2adb,
                                              (int*)(ws + o_degddo), ws + o_hd2, nullptr,
                                              nullptr, nullptr, nullptr, nullptr,
                                              nullptr, nullptr, nullptr);

    head_kernel<<<NDEV / 4, 256, 0, stream>>>(ws + o_hd2, a1W, a1b, a2W, a2b, out_logits);

    softmax_stats_kernel<<<32, 1024, 0, stream>>>(out_logits, ws + o_smax,
                                                  (int*)(ws + o_sargm), ws + o_ssum);
    final_kernel<<<65536 / 256, 256, 0, stream>>>(out_logits, ws + o_smax,
                                                  (int*)(ws + o_sargm), ws + o_ssum,
                                                  out_hard, out_soft);
    (void)in_sizes; (void)n_in; (void)out_size; (void)ws_size;
}